// Round 5
// baseline (1995.736 us; speedup 1.0000x reference)
//
#include <hip/hip_runtime.h>

#define N_NODES 100000
#define E_EDGES 3200000
#define IN_F 128
#define HID 32
#define PROP 8

#define WIN 16384          // nodes per histogram window (64 KB LDS)
#define NWIN 7             // 7*16384 = 114688 >= N
#define HS 16              // edge slices for histogram

#define MB_ROWS 64
#define MB_BLOCKS ((N_NODES + MB_ROWS - 1) / MB_ROWS)   // 1563
#define SCB 98             // scan blocks: 98*1024 >= N

#define FW_WIN 12500       // dst-window size for fill
#define FW_NW 8            // 8 windows cover N exactly
#define FW_SLICES 128      // slices per graph; 3.2M/128 = 25000 edges/slice

// ---------- windowed degree histogram: LDS-aggregated, coalesced flush ----------
__global__ __launch_bounds__(256) void hist_kernel(const int* __restrict__ s, const int* __restrict__ d,
        const int* __restrict__ ns, const int* __restrict__ nd, int* __restrict__ degs) {
    __shared__ int lh[WIN];
    int b = blockIdx.x;
    int w = b % NWIN;
    int st = (b / NWIN) % 4;
    int sl = b / (NWIN * 4);
    const int* p = (st == 0) ? s : (st == 1) ? d : (st == 2) ? ns : nd;
    for (int i = threadIdx.x; i < WIN; i += 256) lh[i] = 0;
    __syncthreads();
    const int lo = w * WIN;
    const int per = E_EDGES / HS;
    const int4* p4 = (const int4*)(p + sl * per);
    for (int i = threadIdx.x; i < per / 4; i += 256) {
        int4 v = p4[i];
        int a;
        a = v.x - lo; if ((unsigned)a < WIN) atomicAdd(&lh[a], 1);
        a = v.y - lo; if ((unsigned)a < WIN) atomicAdd(&lh[a], 1);
        a = v.z - lo; if ((unsigned)a < WIN) atomicAdd(&lh[a], 1);
        a = v.w - lo; if ((unsigned)a < WIN) atomicAdd(&lh[a], 1);
    }
    __syncthreads();
    int* g = degs + st * N_NODES;
    for (int i = threadIdx.x; i < WIN; i += 256) {
        int idx = lo + i;
        if (idx < N_NODES && lh[i]) atomicAdd(&g[idx], lh[i]);
    }
}

__global__ void inv_sqrt_kernel(const int* __restrict__ deg, float* __restrict__ inv, int n) {
    int i = blockIdx.x * blockDim.x + threadIdx.x;
    if (i < n) inv[i] = rsqrtf(fmaxf((float)deg[i], 1.0f));
}

// ---------- 3-stage parallel scan of combined in-degree ----------
__global__ __launch_bounds__(1024) void scanA_kernel(const int* __restrict__ degs,
        int* __restrict__ row_ptr, int* __restrict__ blockSums) {
    __shared__ int sh[1024];
    int t = threadIdx.x, b = blockIdx.x;
    int i = b * 1024 + t;
    int v = (i < N_NODES) ? (degs[N_NODES + i] + degs[3 * N_NODES + i]) : 0;
    sh[t] = v;
    __syncthreads();
    for (int off = 1; off < 1024; off <<= 1) {
        int u = (t >= off) ? sh[t - off] : 0;
        __syncthreads();
        sh[t] += u;
        __syncthreads();
    }
    if (i < N_NODES) row_ptr[i] = sh[t] - v;
    if (t == 1023) blockSums[b] = sh[1023];
}

__global__ __launch_bounds__(128) void scanB_kernel(const int* __restrict__ blockSums,
        int* __restrict__ blockOff) {
    __shared__ int sh[128];
    int t = threadIdx.x;
    int v = (t < SCB) ? blockSums[t] : 0;
    sh[t] = v;
    __syncthreads();
    for (int off = 1; off < 128; off <<= 1) {
        int u = (t >= off) ? sh[t - off] : 0;
        __syncthreads();
        sh[t] += u;
        __syncthreads();
    }
    if (t < SCB) blockOff[t] = sh[t] - v;
}

__global__ __launch_bounds__(1024) void scanC_kernel(int* __restrict__ row_ptr,
        const int* __restrict__ blockOff, int* __restrict__ cursor) {
    int b = blockIdx.x, t = threadIdx.x;
    int i = b * 1024 + t;
    if (i < N_NODES) {
        int v = row_ptr[i] + blockOff[b];
        row_ptr[i] = v;
        cursor[i] = v;
    }
    if (i == 0) row_ptr[N_NODES] = 2 * E_EDGES;
}

// ---------- dst-windowed placement: cursor + rec writes clustered per window ----------
__global__ __launch_bounds__(256) void fillw_kernel(const int* __restrict__ src, const int* __restrict__ dst,
        const int* __restrict__ nsrc, const int* __restrict__ ndst,
        const float* __restrict__ invs, int* __restrict__ cursor, int2* __restrict__ rec) {
    int b = blockIdx.x;
    int g = b >> 7;                       // 0: pos, 1: neg
    int s = b & 127;                      // slice
    const int* sp = (g ? nsrc : src) + s * (E_EDGES / FW_SLICES);
    const int* dp = (g ? ndst : dst) + s * (E_EDGES / FW_SLICES);
    const float* io = invs + (g ? 2 * N_NODES : 0);
    const float* ii = invs + (g ? 3 * N_NODES : N_NODES);
    const float sign = g ? -1.f : 1.f;
    const int4* dp4 = (const int4*)dp;
    const int nq = (E_EDGES / FW_SLICES) / 4;   // 6250
    for (int w = 0; w < FW_NW; ++w) {
        int lo = w * FW_WIN;
        for (int i = threadIdx.x; i < nq; i += 256) {
            int4 dv = dp4[i];
            int e = i * 4;
            #pragma unroll
            for (int j = 0; j < 4; ++j) {
                int v = (j == 0) ? dv.x : (j == 1) ? dv.y : (j == 2) ? dv.z : dv.w;
                if ((unsigned)(v - lo) < FW_WIN) {
                    int u = sp[e + j];
                    float c = sign * io[u] * ii[v];
                    int p = atomicAdd(&cursor[v], 1);
                    rec[p] = make_int2(u, __float_as_int(c));
                }
            }
        }
        __syncthreads();                  // keep block's waves window-synchronized
    }
}

// ---------- MLP stage 1 ----------
__global__ __launch_bounds__(256) void mlp1_kernel(const float* __restrict__ in_feat,
        const float* __restrict__ W1, const float* __restrict__ b1,
        float* __restrict__ x, float* __restrict__ partials) {
    __shared__ float4 sRow4[MB_ROWS * 32];
    __shared__ float  sW1t[32 * 132];
    int tid = threadIdx.x;
    for (int idx = tid; idx < IN_F * HID; idx += 256) {
        int j = idx >> 5, k = idx & 31;
        sW1t[k * 132 + j] = W1[idx];
    }
    int nb = blockIdx.x * MB_ROWS;
    const float4* inf4 = (const float4*)in_feat;
    for (int idx = tid; idx < MB_ROWS * 32; idx += 256) {
        int row = idx >> 5, q = idx & 31;
        int g = nb + row;
        float4 v = (g < N_NODES) ? inf4[(size_t)g * 32 + q] : make_float4(0.f, 0.f, 0.f, 0.f);
        sRow4[row * 32 + (q ^ (row & 31))] = v;
    }
    __syncthreads();
    int rt = tid & 31, kt = tid >> 5;
    int k0 = kt * 4;
    float acc[2][4] = {{0.f}};
    const float4* w0p = (const float4*)&sW1t[(k0 + 0) * 132];
    const float4* w1p = (const float4*)&sW1t[(k0 + 1) * 132];
    const float4* w2p = (const float4*)&sW1t[(k0 + 2) * 132];
    const float4* w3p = (const float4*)&sW1t[(k0 + 3) * 132];
    #pragma unroll 4
    for (int jq = 0; jq < 32; ++jq) {
        int pq = jq ^ rt;
        float4 a0 = sRow4[rt * 32 + pq];
        float4 a1 = sRow4[(rt + 32) * 32 + pq];
        float4 w0 = w0p[jq], w1 = w1p[jq], w2 = w2p[jq], w3 = w3p[jq];
        acc[0][0] += a0.x*w0.x + a0.y*w0.y + a0.z*w0.z + a0.w*w0.w;
        acc[0][1] += a0.x*w1.x + a0.y*w1.y + a0.z*w1.z + a0.w*w1.w;
        acc[0][2] += a0.x*w2.x + a0.y*w2.y + a0.z*w2.z + a0.w*w2.w;
        acc[0][3] += a0.x*w3.x + a0.y*w3.y + a0.z*w3.z + a0.w*w3.w;
        acc[1][0] += a1.x*w0.x + a1.y*w0.y + a1.z*w0.z + a1.w*w0.w;
        acc[1][1] += a1.x*w1.x + a1.y*w1.y + a1.z*w1.z + a1.w*w1.w;
        acc[1][2] += a1.x*w2.x + a1.y*w2.y + a1.z*w2.z + a1.w*w2.w;
        acc[1][3] += a1.x*w3.x + a1.y*w3.y + a1.z*w3.z + a1.w*w3.w;
    }
    float bb[4] = { b1[k0], b1[k0 + 1], b1[k0 + 2], b1[k0 + 3] };
    float s[4] = {0.f, 0.f, 0.f, 0.f}, ss[4] = {0.f, 0.f, 0.f, 0.f};
    #pragma unroll
    for (int i = 0; i < 2; ++i) {
        int row = nb + rt + 32 * i;
        if (row < N_NODES) {
            float4 o;
            o.x = acc[i][0] + bb[0];
            o.y = acc[i][1] + bb[1];
            o.z = acc[i][2] + bb[2];
            o.w = acc[i][3] + bb[3];
            *(float4*)&x[(size_t)row * HID + k0] = o;
            s[0] += o.x; ss[0] += o.x * o.x;
            s[1] += o.y; ss[1] += o.y * o.y;
            s[2] += o.z; ss[2] += o.z * o.z;
            s[3] += o.w; ss[3] += o.w * o.w;
        }
    }
    for (int off = 16; off; off >>= 1) {
        #pragma unroll
        for (int c = 0; c < 4; ++c) {
            s[c]  += __shfl_down(s[c],  off, 32);
            ss[c] += __shfl_down(ss[c], off, 32);
        }
    }
    if (rt == 0) {
        float* pb = partials + (size_t)blockIdx.x * 64;
        #pragma unroll
        for (int c = 0; c < 4; ++c) {
            pb[k0 + c]      = s[c];
            pb[32 + k0 + c] = ss[c];
        }
    }
}

// ---------- reduce partials -> BN scale/shift ----------
__global__ __launch_bounds__(256) void bnparam_kernel(const float* __restrict__ partials,
        const float* __restrict__ gamma, const float* __restrict__ beta, float* __restrict__ params) {
    __shared__ float red[4][64];
    int t = threadIdx.x;
    int col = t & 63, ch = t >> 6;
    float sum = 0.f;
    for (int g = ch; g < MB_BLOCKS; g += 4) sum += partials[(size_t)g * 64 + col];
    red[ch][col] = sum;
    __syncthreads();
    if (t < 64) red[0][t] = red[0][t] + red[1][t] + red[2][t] + red[3][t];
    __syncthreads();
    if (t < HID) {
        float mu  = red[0][t] * (1.0f / (float)N_NODES);
        float var = red[0][t + 32] * (1.0f / (float)N_NODES) - mu * mu;
        float sg = gamma[t] * rsqrtf(var + 1e-5f);
        params[t]       = sg;
        params[HID + t] = beta[t] - mu * sg;
    }
}

// ---------- MLP stage 2 ----------
__global__ __launch_bounds__(256) void mlp2_kernel(const float* __restrict__ x,
        const float* __restrict__ params, const float* __restrict__ W2,
        const float* __restrict__ b2, float* __restrict__ ori_h) {
    __shared__ float sW2[HID * HID];
    __shared__ float sXn[8][HID];
    int tid = threadIdx.x;
    for (int i = tid; i < HID * HID; i += 256) sW2[i] = W2[i];
    int nb = blockIdx.x * 8;
    int k = tid & 31, r = tid >> 5;
    float v = x[(size_t)(nb + r) * HID + k];
    v = fmaxf(fmaf(v, params[k], params[HID + k]), 0.f);
    sXn[r][k] = v;
    __syncthreads();
    float acc = b2[k];
    #pragma unroll
    for (int j = 0; j < HID; ++j) acc = fmaf(sXn[r][j], sW2[j * HID + k], acc);
    ori_h[(size_t)(nb + r) * HID + k] = acc;
}

// ---------- propagation: half-wave per node, 8-way ILP gather ----------
__global__ __launch_bounds__(256) void gather_kernel(const int* __restrict__ row_ptr,
        const int2* __restrict__ rec, const float* __restrict__ h,
        const float* __restrict__ ori, float* __restrict__ hn) {
    int tid = threadIdx.x;
    int node = blockIdx.x * 8 + (tid >> 5);
    int f = tid & 31;
    int beg = row_ptr[node], end = row_ptr[node + 1];
    float acc0 = 0.f, acc1 = 0.f, acc2 = 0.f, acc3 = 0.f;
    float acc4 = 0.f, acc5 = 0.f, acc6 = 0.f, acc7 = 0.f;
    int i = beg;
    if ((i & 1) && i < end) {                    // align to 16 B
        int2 r = rec[i];
        acc0 = fmaf(__int_as_float(r.y), h[r.x * HID + f], acc0);
        ++i;
    }
    for (; i + 8 <= end; i += 8) {
        int4 a = *(const int4*)(rec + i);
        int4 b = *(const int4*)(rec + i + 2);
        int4 c = *(const int4*)(rec + i + 4);
        int4 d = *(const int4*)(rec + i + 6);
        acc0 = fmaf(__int_as_float(a.y), h[a.x * HID + f], acc0);
        acc1 = fmaf(__int_as_float(a.w), h[a.z * HID + f], acc1);
        acc2 = fmaf(__int_as_float(b.y), h[b.x * HID + f], acc2);
        acc3 = fmaf(__int_as_float(b.w), h[b.z * HID + f], acc3);
        acc4 = fmaf(__int_as_float(c.y), h[c.x * HID + f], acc4);
        acc5 = fmaf(__int_as_float(c.w), h[c.z * HID + f], acc5);
        acc6 = fmaf(__int_as_float(d.y), h[d.x * HID + f], acc6);
        acc7 = fmaf(__int_as_float(d.w), h[d.z * HID + f], acc7);
    }
    for (; i + 4 <= end; i += 4) {
        int4 a = *(const int4*)(rec + i);
        int4 b = *(const int4*)(rec + i + 2);
        acc0 = fmaf(__int_as_float(a.y), h[a.x * HID + f], acc0);
        acc1 = fmaf(__int_as_float(a.w), h[a.z * HID + f], acc1);
        acc2 = fmaf(__int_as_float(b.y), h[b.x * HID + f], acc2);
        acc3 = fmaf(__int_as_float(b.w), h[b.z * HID + f], acc3);
    }
    for (; i < end; ++i) {
        int2 r = rec[i];
        acc0 = fmaf(__int_as_float(r.y), h[r.x * HID + f], acc0);
    }
    int o = node * HID + f;
    float r0 = (acc0 + acc1) + (acc2 + acc3);
    float r1 = (acc4 + acc5) + (acc6 + acc7);
    hn[o] = ori[o] + (r0 + r1);
}

extern "C" void kernel_launch(void* const* d_in, const int* in_sizes, int n_in,
                              void* d_out, int out_size, void* d_ws, size_t ws_size,
                              hipStream_t stream) {
    const float* in_feat = (const float*)d_in[0];
    const float* W1    = (const float*)d_in[1];
    const float* b1    = (const float*)d_in[2];
    const float* gamma = (const float*)d_in[3];
    const float* beta  = (const float*)d_in[4];
    const float* W2    = (const float*)d_in[5];
    const float* b2    = (const float*)d_in[6];
    const int* src  = (const int*)d_in[7];
    const int* dst  = (const int*)d_in[8];
    const int* nsrc = (const int*)d_in[9];
    const int* ndst = (const int*)d_in[10];
    float* out = (float*)d_out;

    // ---- workspace layout ----
    float* ws      = (float*)d_ws;
    float* x       = ws;                                   // N*32
    float* ori_h   = x + (size_t)N_NODES * HID;            // N*32
    float* invs    = ori_h + (size_t)N_NODES * HID;        // 4*N
    float* params  = invs + 4 * (size_t)N_NODES;           // 64
    float* partials= params + 2 * HID;                     // MB_BLOCKS*64
    int*   degs    = (int*)(partials + (size_t)MB_BLOCKS * 64);  // 4*N
    int*   row_ptr = degs + 4 * N_NODES;                   // N+1
    int*   cursor  = row_ptr + N_NODES + 2;                // N
    int*   blockSums = cursor + N_NODES;                   // SCB
    int*   blockOff  = blockSums + 128;                    // SCB
    uintptr_t rp  = (uintptr_t)(blockOff + 128);
    rp = (rp + 15) & ~(uintptr_t)15;
    int2*  rec    = (int2*)rp;                             // 2*E records (51.2 MB)

    hipMemsetAsync(degs, 0, 4 * (size_t)N_NODES * sizeof(int), stream);

    hist_kernel<<<NWIN * 4 * HS, 256, 0, stream>>>(src, dst, nsrc, ndst, degs);
    inv_sqrt_kernel<<<(4 * N_NODES + 255) / 256, 256, 0, stream>>>(degs, invs, 4 * N_NODES);
    scanA_kernel<<<SCB, 1024, 0, stream>>>(degs, row_ptr, blockSums);
    scanB_kernel<<<1, 128, 0, stream>>>(blockSums, blockOff);
    scanC_kernel<<<SCB, 1024, 0, stream>>>(row_ptr, blockOff, cursor);
    fillw_kernel<<<2 * FW_SLICES, 256, 0, stream>>>(src, dst, nsrc, ndst, invs, cursor, rec);

    mlp1_kernel<<<MB_BLOCKS, 256, 0, stream>>>(in_feat, W1, b1, x, partials);
    bnparam_kernel<<<1, 256, 0, stream>>>(partials, gamma, beta, params);
    mlp2_kernel<<<N_NODES / 8, 256, 0, stream>>>(x, params, W2, b2, ori_h);

    const float* h = ori_h;
    for (int it = 0; it < PROP; ++it) {
        float* hn = (it & 1) ? out : x;      // last (it=7, odd) lands in out
        gather_kernel<<<N_NODES / 8, 256, 0, stream>>>(row_ptr, rec, h, ori_h, hn);
        h = hn;
    }
}

// Round 6
// 1423.540 us; speedup vs baseline: 1.4020x; 1.4020x over previous
//
#include <hip/hip_runtime.h>
#include <hip/hip_fp16.h>

#define N_NODES 100000
#define E_EDGES 3200000
#define IN_F 128
#define HID 32
#define PROP 8

#define WIN 16384          // nodes per histogram window (64 KB LDS)
#define NWIN 7             // 7*16384 = 114688 >= N
#define HS 16              // edge slices for histogram

#define MB_ROWS 64
#define MB_BLOCKS ((N_NODES + MB_ROWS - 1) / MB_ROWS)   // 1563
#define SCB 98             // scan blocks: 98*1024 >= N

// ---------- windowed degree histogram: LDS-aggregated, coalesced flush ----------
__global__ __launch_bounds__(256) void hist_kernel(const int* __restrict__ s, const int* __restrict__ d,
        const int* __restrict__ ns, const int* __restrict__ nd, int* __restrict__ degs) {
    __shared__ int lh[WIN];
    int b = blockIdx.x;
    int w = b % NWIN;
    int st = (b / NWIN) % 4;
    int sl = b / (NWIN * 4);
    const int* p = (st == 0) ? s : (st == 1) ? d : (st == 2) ? ns : nd;
    for (int i = threadIdx.x; i < WIN; i += 256) lh[i] = 0;
    __syncthreads();
    const int lo = w * WIN;
    const int per = E_EDGES / HS;
    const int4* p4 = (const int4*)(p + sl * per);
    for (int i = threadIdx.x; i < per / 4; i += 256) {
        int4 v = p4[i];
        int a;
        a = v.x - lo; if ((unsigned)a < WIN) atomicAdd(&lh[a], 1);
        a = v.y - lo; if ((unsigned)a < WIN) atomicAdd(&lh[a], 1);
        a = v.z - lo; if ((unsigned)a < WIN) atomicAdd(&lh[a], 1);
        a = v.w - lo; if ((unsigned)a < WIN) atomicAdd(&lh[a], 1);
    }
    __syncthreads();
    int* g = degs + st * N_NODES;
    for (int i = threadIdx.x; i < WIN; i += 256) {
        int idx = lo + i;
        if (idx < N_NODES && lh[i]) atomicAdd(&g[idx], lh[i]);
    }
}

__global__ void inv_sqrt_kernel(const int* __restrict__ deg, float* __restrict__ inv, int n) {
    int i = blockIdx.x * blockDim.x + threadIdx.x;
    if (i < n) inv[i] = rsqrtf(fmaxf((float)deg[i], 1.0f));
}

// ---------- 3-stage parallel scan of combined in-degree ----------
__global__ __launch_bounds__(1024) void scanA_kernel(const int* __restrict__ degs,
        int* __restrict__ row_ptr, int* __restrict__ blockSums) {
    __shared__ int sh[1024];
    int t = threadIdx.x, b = blockIdx.x;
    int i = b * 1024 + t;
    int v = (i < N_NODES) ? (degs[N_NODES + i] + degs[3 * N_NODES + i]) : 0;
    sh[t] = v;
    __syncthreads();
    for (int off = 1; off < 1024; off <<= 1) {
        int u = (t >= off) ? sh[t - off] : 0;
        __syncthreads();
        sh[t] += u;
        __syncthreads();
    }
    if (i < N_NODES) row_ptr[i] = sh[t] - v;
    if (t == 1023) blockSums[b] = sh[1023];
}

__global__ __launch_bounds__(128) void scanB_kernel(const int* __restrict__ blockSums,
        int* __restrict__ blockOff) {
    __shared__ int sh[128];
    int t = threadIdx.x;
    int v = (t < SCB) ? blockSums[t] : 0;
    sh[t] = v;
    __syncthreads();
    for (int off = 1; off < 128; off <<= 1) {
        int u = (t >= off) ? sh[t - off] : 0;
        __syncthreads();
        sh[t] += u;
        __syncthreads();
    }
    if (t < SCB) blockOff[t] = sh[t] - v;
}

__global__ __launch_bounds__(1024) void scanC_kernel(int* __restrict__ row_ptr,
        const int* __restrict__ blockOff, int* __restrict__ cursor) {
    int b = blockIdx.x, t = threadIdx.x;
    int i = b * 1024 + t;
    if (i < N_NODES) {
        int v = row_ptr[i] + blockOff[b];
        row_ptr[i] = v;
        cursor[i] = v;
    }
    if (i == 0) row_ptr[N_NODES] = 2 * E_EDGES;
}

// ---------- placement: both graphs in one dispatch (round-4 fill2, reverted) ----------
__global__ __launch_bounds__(256) void fill2_kernel(const int* __restrict__ src, const int* __restrict__ dst,
        const int* __restrict__ nsrc, const int* __restrict__ ndst,
        const float* __restrict__ invs, int* __restrict__ cursor, int2* __restrict__ rec) {
    int e = blockIdx.x * 256 + threadIdx.x;
    int u, v; float sign; const float* io; const float* ii;
    if (e < E_EDGES) {
        u = src[e]; v = dst[e]; sign = 1.f;
        io = invs; ii = invs + N_NODES;
    } else {
        int e2 = e - E_EDGES;
        u = nsrc[e2]; v = ndst[e2]; sign = -1.f;
        io = invs + 2 * N_NODES; ii = invs + 3 * N_NODES;
    }
    float c = sign * io[u] * ii[v];
    int p = atomicAdd(&cursor[v], 1);
    rec[p] = make_int2(u, __float_as_int(c));
}

// ---------- MLP stage 1 ----------
__global__ __launch_bounds__(256) void mlp1_kernel(const float* __restrict__ in_feat,
        const float* __restrict__ W1, const float* __restrict__ b1,
        float* __restrict__ x, float* __restrict__ partials) {
    __shared__ float4 sRow4[MB_ROWS * 32];
    __shared__ float  sW1t[32 * 132];
    int tid = threadIdx.x;
    for (int idx = tid; idx < IN_F * HID; idx += 256) {
        int j = idx >> 5, k = idx & 31;
        sW1t[k * 132 + j] = W1[idx];
    }
    int nb = blockIdx.x * MB_ROWS;
    const float4* inf4 = (const float4*)in_feat;
    for (int idx = tid; idx < MB_ROWS * 32; idx += 256) {
        int row = idx >> 5, q = idx & 31;
        int g = nb + row;
        float4 v = (g < N_NODES) ? inf4[(size_t)g * 32 + q] : make_float4(0.f, 0.f, 0.f, 0.f);
        sRow4[row * 32 + (q ^ (row & 31))] = v;
    }
    __syncthreads();
    int rt = tid & 31, kt = tid >> 5;
    int k0 = kt * 4;
    float acc[2][4] = {{0.f}};
    const float4* w0p = (const float4*)&sW1t[(k0 + 0) * 132];
    const float4* w1p = (const float4*)&sW1t[(k0 + 1) * 132];
    const float4* w2p = (const float4*)&sW1t[(k0 + 2) * 132];
    const float4* w3p = (const float4*)&sW1t[(k0 + 3) * 132];
    #pragma unroll 4
    for (int jq = 0; jq < 32; ++jq) {
        int pq = jq ^ rt;
        float4 a0 = sRow4[rt * 32 + pq];
        float4 a1 = sRow4[(rt + 32) * 32 + pq];
        float4 w0 = w0p[jq], w1 = w1p[jq], w2 = w2p[jq], w3 = w3p[jq];
        acc[0][0] += a0.x*w0.x + a0.y*w0.y + a0.z*w0.z + a0.w*w0.w;
        acc[0][1] += a0.x*w1.x + a0.y*w1.y + a0.z*w1.z + a0.w*w1.w;
        acc[0][2] += a0.x*w2.x + a0.y*w2.y + a0.z*w2.z + a0.w*w2.w;
        acc[0][3] += a0.x*w3.x + a0.y*w3.y + a0.z*w3.z + a0.w*w3.w;
        acc[1][0] += a1.x*w0.x + a1.y*w0.y + a1.z*w0.z + a1.w*w0.w;
        acc[1][1] += a1.x*w1.x + a1.y*w1.y + a1.z*w1.z + a1.w*w1.w;
        acc[1][2] += a1.x*w2.x + a1.y*w2.y + a1.z*w2.z + a1.w*w2.w;
        acc[1][3] += a1.x*w3.x + a1.y*w3.y + a1.z*w3.z + a1.w*w3.w;
    }
    float bb[4] = { b1[k0], b1[k0 + 1], b1[k0 + 2], b1[k0 + 3] };
    float s[4] = {0.f, 0.f, 0.f, 0.f}, ss[4] = {0.f, 0.f, 0.f, 0.f};
    #pragma unroll
    for (int i = 0; i < 2; ++i) {
        int row = nb + rt + 32 * i;
        if (row < N_NODES) {
            float4 o;
            o.x = acc[i][0] + bb[0];
            o.y = acc[i][1] + bb[1];
            o.z = acc[i][2] + bb[2];
            o.w = acc[i][3] + bb[3];
            *(float4*)&x[(size_t)row * HID + k0] = o;
            s[0] += o.x; ss[0] += o.x * o.x;
            s[1] += o.y; ss[1] += o.y * o.y;
            s[2] += o.z; ss[2] += o.z * o.z;
            s[3] += o.w; ss[3] += o.w * o.w;
        }
    }
    for (int off = 16; off; off >>= 1) {
        #pragma unroll
        for (int c = 0; c < 4; ++c) {
            s[c]  += __shfl_down(s[c],  off, 32);
            ss[c] += __shfl_down(ss[c], off, 32);
        }
    }
    if (rt == 0) {
        float* pb = partials + (size_t)blockIdx.x * 64;
        #pragma unroll
        for (int c = 0; c < 4; ++c) {
            pb[k0 + c]      = s[c];
            pb[32 + k0 + c] = ss[c];
        }
    }
}

// ---------- reduce partials -> BN scale/shift ----------
__global__ __launch_bounds__(256) void bnparam_kernel(const float* __restrict__ partials,
        const float* __restrict__ gamma, const float* __restrict__ beta, float* __restrict__ params) {
    __shared__ float red[4][64];
    int t = threadIdx.x;
    int col = t & 63, ch = t >> 6;
    float sum = 0.f;
    for (int g = ch; g < MB_BLOCKS; g += 4) sum += partials[(size_t)g * 64 + col];
    red[ch][col] = sum;
    __syncthreads();
    if (t < 64) red[0][t] = red[0][t] + red[1][t] + red[2][t] + red[3][t];
    __syncthreads();
    if (t < HID) {
        float mu  = red[0][t] * (1.0f / (float)N_NODES);
        float var = red[0][t + 32] * (1.0f / (float)N_NODES) - mu * mu;
        float sg = gamma[t] * rsqrtf(var + 1e-5f);
        params[t]       = sg;
        params[HID + t] = beta[t] - mu * sg;
    }
}

// ---------- MLP stage 2: ori_h (fp32) + initial h (fp16) ----------
__global__ __launch_bounds__(256) void mlp2_kernel(const float* __restrict__ x,
        const float* __restrict__ params, const float* __restrict__ W2,
        const float* __restrict__ b2, float* __restrict__ ori_h, __half* __restrict__ h16) {
    __shared__ float sW2[HID * HID];
    __shared__ float sXn[8][HID];
    int tid = threadIdx.x;
    for (int i = tid; i < HID * HID; i += 256) sW2[i] = W2[i];
    int nb = blockIdx.x * 8;
    int k = tid & 31, r = tid >> 5;
    float v = x[(size_t)(nb + r) * HID + k];
    v = fmaxf(fmaf(v, params[k], params[HID + k]), 0.f);
    sXn[r][k] = v;
    __syncthreads();
    float acc = b2[k];
    #pragma unroll
    for (int j = 0; j < HID; ++j) acc = fmaf(sXn[r][j], sW2[j * HID + k], acc);
    int o = (nb + r) * HID + k;
    ori_h[o] = acc;
    h16[o] = __float2half(acc);
}

// ---------- propagation: half-wave per node, 8-way ILP, fp16 h ----------
__global__ __launch_bounds__(256) void gather_kernel(const int* __restrict__ row_ptr,
        const int2* __restrict__ rec, const __half* __restrict__ h,
        const float* __restrict__ ori, __half* __restrict__ hn16, float* __restrict__ out32) {
    int tid = threadIdx.x;
    int node = blockIdx.x * 8 + (tid >> 5);
    int f = tid & 31;
    int beg = row_ptr[node], end = row_ptr[node + 1];
    float acc0 = 0.f, acc1 = 0.f, acc2 = 0.f, acc3 = 0.f;
    float acc4 = 0.f, acc5 = 0.f, acc6 = 0.f, acc7 = 0.f;
    int i = beg;
    if ((i & 1) && i < end) {                    // align rec reads to 16 B
        int2 r = rec[i];
        acc0 = fmaf(__int_as_float(r.y), __half2float(h[r.x * HID + f]), acc0);
        ++i;
    }
    for (; i + 8 <= end; i += 8) {
        int4 a = *(const int4*)(rec + i);
        int4 b = *(const int4*)(rec + i + 2);
        int4 c = *(const int4*)(rec + i + 4);
        int4 d = *(const int4*)(rec + i + 6);
        float h0 = __half2float(h[a.x * HID + f]);
        float h1 = __half2float(h[a.z * HID + f]);
        float h2 = __half2float(h[b.x * HID + f]);
        float h3 = __half2float(h[b.z * HID + f]);
        float h4 = __half2float(h[c.x * HID + f]);
        float h5 = __half2float(h[c.z * HID + f]);
        float h6 = __half2float(h[d.x * HID + f]);
        float h7 = __half2float(h[d.z * HID + f]);
        acc0 = fmaf(__int_as_float(a.y), h0, acc0);
        acc1 = fmaf(__int_as_float(a.w), h1, acc1);
        acc2 = fmaf(__int_as_float(b.y), h2, acc2);
        acc3 = fmaf(__int_as_float(b.w), h3, acc3);
        acc4 = fmaf(__int_as_float(c.y), h4, acc4);
        acc5 = fmaf(__int_as_float(c.w), h5, acc5);
        acc6 = fmaf(__int_as_float(d.y), h6, acc6);
        acc7 = fmaf(__int_as_float(d.w), h7, acc7);
    }
    for (; i + 4 <= end; i += 4) {
        int4 a = *(const int4*)(rec + i);
        int4 b = *(const int4*)(rec + i + 2);
        acc0 = fmaf(__int_as_float(a.y), __half2float(h[a.x * HID + f]), acc0);
        acc1 = fmaf(__int_as_float(a.w), __half2float(h[a.z * HID + f]), acc1);
        acc2 = fmaf(__int_as_float(b.y), __half2float(h[b.x * HID + f]), acc2);
        acc3 = fmaf(__int_as_float(b.w), __half2float(h[b.z * HID + f]), acc3);
    }
    for (; i < end; ++i) {
        int2 r = rec[i];
        acc0 = fmaf(__int_as_float(r.y), __half2float(h[r.x * HID + f]), acc0);
    }
    int o = node * HID + f;
    float r0 = (acc0 + acc1) + (acc2 + acc3);
    float r1 = (acc4 + acc5) + (acc6 + acc7);
    float res = ori[o] + (r0 + r1);
    if (out32) out32[o] = res;          // final iteration: fp32 output
    else hn16[o] = __float2half(res);   // intermediate: fp16
}

extern "C" void kernel_launch(void* const* d_in, const int* in_sizes, int n_in,
                              void* d_out, int out_size, void* d_ws, size_t ws_size,
                              hipStream_t stream) {
    const float* in_feat = (const float*)d_in[0];
    const float* W1    = (const float*)d_in[1];
    const float* b1    = (const float*)d_in[2];
    const float* gamma = (const float*)d_in[3];
    const float* beta  = (const float*)d_in[4];
    const float* W2    = (const float*)d_in[5];
    const float* b2    = (const float*)d_in[6];
    const int* src  = (const int*)d_in[7];
    const int* dst  = (const int*)d_in[8];
    const int* nsrc = (const int*)d_in[9];
    const int* ndst = (const int*)d_in[10];
    float* out = (float*)d_out;

    // ---- workspace layout ----
    float* ws      = (float*)d_ws;
    float* x       = ws;                                   // N*32
    float* ori_h   = x + (size_t)N_NODES * HID;            // N*32
    float* invs    = ori_h + (size_t)N_NODES * HID;        // 4*N
    float* params  = invs + 4 * (size_t)N_NODES;           // 64
    float* partials= params + 2 * HID;                     // MB_BLOCKS*64
    int*   degs    = (int*)(partials + (size_t)MB_BLOCKS * 64);  // 4*N
    int*   row_ptr = degs + 4 * N_NODES;                   // N+1
    int*   cursor  = row_ptr + N_NODES + 2;                // N
    int*   blockSums = cursor + N_NODES;                   // SCB
    int*   blockOff  = blockSums + 128;                    // SCB
    __half* h16A   = (__half*)(blockOff + 128);            // N*32 fp16
    __half* h16B   = h16A + (size_t)N_NODES * HID;         // N*32 fp16
    uintptr_t rp  = (uintptr_t)(h16B + (size_t)N_NODES * HID);
    rp = (rp + 15) & ~(uintptr_t)15;
    int2*  rec    = (int2*)rp;                             // 2*E records (51.2 MB)

    hipMemsetAsync(degs, 0, 4 * (size_t)N_NODES * sizeof(int), stream);

    hist_kernel<<<NWIN * 4 * HS, 256, 0, stream>>>(src, dst, nsrc, ndst, degs);
    inv_sqrt_kernel<<<(4 * N_NODES + 255) / 256, 256, 0, stream>>>(degs, invs, 4 * N_NODES);
    scanA_kernel<<<SCB, 1024, 0, stream>>>(degs, row_ptr, blockSums);
    scanB_kernel<<<1, 128, 0, stream>>>(blockSums, blockOff);
    scanC_kernel<<<SCB, 1024, 0, stream>>>(row_ptr, blockOff, cursor);
    fill2_kernel<<<2 * E_EDGES / 256, 256, 0, stream>>>(src, dst, nsrc, ndst, invs, cursor, rec);

    mlp1_kernel<<<MB_BLOCKS, 256, 0, stream>>>(in_feat, W1, b1, x, partials);
    bnparam_kernel<<<1, 256, 0, stream>>>(partials, gamma, beta, params);
    mlp2_kernel<<<N_NODES / 8, 256, 0, stream>>>(x, params, W2, b2, ori_h, h16A);

    // 8 propagation passes on fp16 h; final lands fp32 in out
    const __half* h = h16A;
    for (int it = 0; it < PROP; ++it) {
        __half* hn16 = (it & 1) ? h16A : h16B;
        float* o32 = (it == PROP - 1) ? out : nullptr;
        gather_kernel<<<N_NODES / 8, 256, 0, stream>>>(row_ptr, rec, h, ori_h, hn16, o32);
        h = hn16;
    }
}